// Round 9
// baseline (4001.262 us; speedup 1.0000x reference)
//
#include <hip/hip_runtime.h>
#include <stdint.h>

#define B_ 4096
#define T_ 80
#define E_ 100
#define V_ 10000
#define U_ 1024

typedef unsigned short u16;
typedef __attribute__((ext_vector_type(8))) __bf16 bf16x8;
typedef __attribute__((ext_vector_type(4))) float f32x4;

__device__ __forceinline__ float bf2f(u16 u) {
    union { unsigned int i; float f; } v; v.i = ((unsigned int)u) << 16; return v.f;
}
__device__ __forceinline__ u16 f2bf(float f) {
    union { float f; unsigned int i; } v; v.f = f;
    unsigned int x = v.i;
    return (u16)((x + 0x7fffu + ((x >> 16) & 1u)) >> 16);
}

// async global->LDS, 16 B per lane; LDS dest = wave-uniform base + lane*16 (m104 semantics).
__device__ __forceinline__ void load16(const void* g, void* l) {
    __builtin_amdgcn_global_load_lds(
        (__attribute__((address_space(1))) void*)(uintptr_t)g,
        (__attribute__((address_space(3))) void*)(uint32_t)(uintptr_t)l,
        16, 0, 0);
}

// dst[n*Kp + k] = bf16( (k < K) ? src[k*N + n] : 0 )
__global__ void transpose_pad(const float* __restrict__ src, u16* __restrict__ dst,
                              int K, int N, int Kp)
{
    __shared__ u16 tile[32][33];
    const int k0 = blockIdx.x * 32;
    const int n0 = blockIdx.y * 32;
    const int tx = threadIdx.x & 31;
    const int ty = threadIdx.x >> 5;
#pragma unroll
    for (int i = 0; i < 4; i++) {
        int k = k0 + ty + i * 8;
        tile[ty + i * 8][tx] = (k < K) ? f2bf(src[(size_t)k * N + (n0 + tx)]) : (u16)0;
    }
    __syncthreads();
#pragma unroll
    for (int i = 0; i < 4; i++) {
        int n = n0 + ty + i * 8;
        dst[(size_t)n * Kp + (k0 + tx)] = tile[tx][ty + i * 8];
    }
}

__global__ void embed_pad(const float* __restrict__ emb, u16* __restrict__ dst)
{
    int id = blockIdx.x * 256 + threadIdx.x;
    int v = id >> 7, k = id & 127;
    dst[id] = (k < E_) ? f2bf(emb[v * E_ + k]) : (u16)0;
}

// Fused phase p (independent sub-steps):
//   layer0: h0[p]   = tanh(embP[idx_p] @ Wx0 + h0[p-1] @ Wh0 + b0)   (if do0)
//   layer1: h1[p-1] = tanh(h0[p-1] @ Wx1 + h1[p-2] @ Wh1 + b1)       (if do1)
// Tile M=128 x N=64, BK=32, QUAD-buffered LDS (4x12 KB = 48 KB -> 3 blocks/CU).
// Prefetch distance 2 with manual s_waitcnt vmcnt(3) + s_barrier (never vmcnt(0) except
// last iter): each wave issues exactly 3 global_load_lds per stage; the barrier waits only
// the oldest stage, keeping the next stage's loads in flight across it (Little's law: 2x
// in-flight bytes vs __syncthreads' vmcnt(0) drain). NB=4 ring: stage(u+2) writes the
// buffer last read at compute(u-2), two barriers back -> race-free. In-order DS completion
// + compiler lgkmcnt-before-MFMA guarantees old ds_reads drain a barrier before reuse.
// XOR swizzle (round-7-proven, 0 conflicts): row r chunk c holds global chunk c^((r>>1)&3).
__global__ void __launch_bounds__(256, 3)
rnn_phase(const u16* __restrict__ embP, const int* __restrict__ idx,
          const u16* __restrict__ Wx0T, const u16* __restrict__ Wh0T, const float* __restrict__ b0,
          const u16* __restrict__ Wx1T, const u16* __restrict__ Wh1T, const float* __restrict__ b1,
          const u16* __restrict__ h0r, u16* __restrict__ h0w,
          const u16* __restrict__ h1r, u16* __restrict__ h1w,
          int do0, int do1)
{
    const int layer = blockIdx.y & 1;
    if (layer ? !do1 : !do0) return;

    __shared__ u16 As[4][128 * 32];   // 4 x 8 KB
    __shared__ u16 Bs[4][64 * 32];    // 4 x 4 KB
    const int tid  = threadIdx.x;
    const int lane = tid & 63;
    const int wave = tid >> 6;
    const int wm = wave >> 1, wn = wave & 1;
    const int m0 = blockIdx.x * 128;
    const int n0 = (blockIdx.y >> 1) * 64;

    const u16 *A1, *W1, *A2, *W2; const float* bias; u16* C; int K1; bool gather;
    if (layer == 0) { A1 = embP; W1 = Wx0T; K1 = 128;  gather = true;  A2 = h0r; W2 = Wh0T; bias = b0; C = h0w; }
    else            { A1 = h0r;  W1 = Wx1T; K1 = 1024; gather = false; A2 = h1r; W2 = Wh1T; bias = b1; C = h1w; }
    const int KB1 = K1 >> 5;            // 32-wide K blocks in first segment (4 or 32)
    const int TOT = KB1 + 32;

    // staging geometry: per stage per wave = 3 calls (A rows [wave*32,+32) in 2 calls of
    // 16 rows; B rows [wave*16,+16) in 1 call). lane -> row += lane>>2, chunk lane&3.
    const int r4 = lane >> 2;           // 0..15
    const int c4 = lane & 3;            // chunk 0..3

    int gv[2];
    if (gather) {
        gv[0] = idx[(size_t)(m0 + wave * 32 + r4) * T_];
        gv[1] = idx[(size_t)(m0 + wave * 32 + 16 + r4) * T_];
    }

    const f32x4 z = {0.f, 0.f, 0.f, 0.f};
    f32x4 acc[4][2];
#pragma unroll
    for (int i = 0; i < 4; i++)
#pragma unroll
        for (int j = 0; j < 2; j++) acc[i][j] = z;

    // loop-invariant fragment read offsets (u16 elems), inverse-swizzled
    const int l15 = lane & 15, q = lane >> 4;
    int offA[4], offB[2];
#pragma unroll
    for (int f = 0; f < 4; f++) {
        const int rA = wm * 64 + f * 16 + l15;
        offA[f] = rA * 32 + ((q ^ ((rA >> 1) & 3)) * 8);
    }
#pragma unroll
    for (int f = 0; f < 2; f++) {
        const int rB = wn * 32 + f * 16 + l15;
        offB[f] = rB * 32 + ((q ^ ((rB >> 1) & 3)) * 8);
    }

    auto stage = [&](int u, int p) {
        u16* Ad = As[p] + wave * 1024;   // 32 rows x 32 elems
        u16* Bd = Bs[p] + wave * 512;    // 16 rows x 32 elems
        if (u < KB1) {
            const int k0 = u * 32;
#pragma unroll
            for (int c = 0; c < 2; c++) {
                const int row = wave * 32 + c * 16 + r4;
                const int scw = (c4 ^ ((row >> 1) & 3)) * 8;
                const u16* ap = gather ? A1 + (size_t)gv[c] * 128 + k0 + scw
                                       : A1 + (size_t)(m0 + row) * K1 + k0 + scw;
                load16(ap, Ad + c * 512);
            }
            const int rowB = wave * 16 + r4;
            const int scwB = (c4 ^ ((rowB >> 1) & 3)) * 8;
            load16(W1 + (size_t)(n0 + rowB) * K1 + k0 + scwB, Bd);
        } else {
            const int k0 = (u - KB1) * 32;
#pragma unroll
            for (int c = 0; c < 2; c++) {
                const int row = wave * 32 + c * 16 + r4;
                const int scw = (c4 ^ ((row >> 1) & 3)) * 8;
                load16(A2 + (size_t)(m0 + row) * U_ + k0 + scw, Ad + c * 512);
            }
            const int rowB = wave * 16 + r4;
            const int scwB = (c4 ^ ((rowB >> 1) & 3)) * 8;
            load16(W2 + (size_t)(n0 + rowB) * U_ + k0 + scwB, Bd);
        }
    };

    stage(0, 0);
    stage(1, 1);

#pragma unroll 1
    for (int u = 0; u < TOT; ++u) {
        const int p = u & 3;
        // drain own stage(u) (3 oldest loads), leave stage(u+1)'s 3 in flight
        if (u + 1 < TOT) __builtin_amdgcn_s_waitcnt(0x0F73);  // vmcnt(3), no exp/lgkm wait
        else             __builtin_amdgcn_s_waitcnt(0x0F70);  // vmcnt(0) on final iter
        __builtin_amdgcn_s_barrier();
        if (u + 2 < TOT) stage(u + 2, (u + 2) & 3);
        bf16x8 a[4], b[2];
#pragma unroll
        for (int f = 0; f < 4; f++)
            a[f] = *reinterpret_cast<const bf16x8*>(As[p] + offA[f]);
#pragma unroll
        for (int f = 0; f < 2; f++)
            b[f] = *reinterpret_cast<const bf16x8*>(Bs[p] + offB[f]);
#pragma unroll
        for (int i = 0; i < 4; i++)
#pragma unroll
            for (int j = 0; j < 2; j++)
                acc[i][j] = __builtin_amdgcn_mfma_f32_16x16x32_bf16(a[i], b[j], acc[i][j], 0, 0, 0);
    }

    // epilogue: bias + tanh, bf16 store (C/D map: col = lane&15, row = (lane>>4)*4 + reg)
#pragma unroll
    for (int j = 0; j < 2; j++) {
        const int col = n0 + wn * 32 + j * 16 + l15;
        const float bv = bias[col];
#pragma unroll
        for (int i = 0; i < 4; i++) {
#pragma unroll
            for (int r = 0; r < 4; r++) {
                const int row = m0 + wm * 64 + i * 16 + (q << 2) + r;
                float x = acc[i][j][r] + bv;
                x = fminf(15.f, fmaxf(-15.f, x));
                float e = __expf(2.f * x);
                C[(size_t)row * U_ + col] = f2bf((e - 1.f) / (e + 1.f));
            }
        }
    }
}

// out[b] = sigmoid( dot(h1[b,:], Wfc) + bfc ), one wave per row; f32 out
__global__ void final_dense(const u16* __restrict__ h1, const float* __restrict__ Wfc,
                            const float* __restrict__ bfc, float* __restrict__ out)
{
    const int lane = threadIdx.x & 63;
    const int wave = threadIdx.x >> 6;
    const int row = blockIdx.x * 4 + wave;
    const u16* hp = h1 + (size_t)row * U_ + lane * 16;
    const float* wp = Wfc + lane * 16;
    float s = 0.f;
#pragma unroll
    for (int i = 0; i < 16; i++) s += bf2f(hp[i]) * wp[i];
#pragma unroll
    for (int off = 32; off; off >>= 1) s += __shfl_down(s, off);
    if (lane == 0) {
        float x = s + bfc[0];
        out[row] = 1.f / (1.f + __expf(-x));
    }
}

extern "C" void kernel_launch(void* const* d_in, const int* in_sizes, int n_in,
                              void* d_out, int out_size, void* d_ws, size_t ws_size,
                              hipStream_t stream)
{
    const int*   inputs = (const int*)d_in[0];
    const float* emb    = (const float*)d_in[1];
    const float* Wx0    = (const float*)d_in[2];
    const float* Wh0    = (const float*)d_in[3];
    const float* b0     = (const float*)d_in[4];
    const float* Wx1    = (const float*)d_in[5];
    const float* Wh1    = (const float*)d_in[6];
    const float* b1     = (const float*)d_in[7];
    const float* Wfc    = (const float*)d_in[8];
    const float* bfc    = (const float*)d_in[9];

    char* ws = (char*)d_ws;
    const size_t MB = 1 << 20;
    u16* h0b[2] = { (u16*)(ws + 0 * MB), (u16*)(ws + 8 * MB) };   // 8 MB each
    u16* h1b[2] = { (u16*)(ws + 16 * MB), (u16*)(ws + 24 * MB) };
    u16* embP = (u16*)(ws + 32 * MB);  // 2.56 MB
    u16* Wx0T = (u16*)(ws + 35 * MB);  // [1024][128]
    u16* Wh0T = (u16*)(ws + 36 * MB);  // [1024][1024]
    u16* Wx1T = (u16*)(ws + 38 * MB);
    u16* Wh1T = (u16*)(ws + 40 * MB);  // ..42 MB

    // phase 0 reads h0[-1] from h0b[1]; phase 1 reads h1[-1] from h1b[1]
    hipMemsetAsync(h0b[1], 0, 8 * MB, stream);
    hipMemsetAsync(h1b[1], 0, 8 * MB, stream);

    embed_pad<<<V_ * 128 / 256, 256, 0, stream>>>(emb, embP);
    transpose_pad<<<dim3(128 / 32, U_ / 32), 256, 0, stream>>>(Wx0, Wx0T, E_, U_, 128);
    transpose_pad<<<dim3(U_ / 32, U_ / 32), 256, 0, stream>>>(Wh0, Wh0T, U_, U_, U_);
    transpose_pad<<<dim3(U_ / 32, U_ / 32), 256, 0, stream>>>(Wx1, Wx1T, U_, U_, U_);
    transpose_pad<<<dim3(U_ / 32, U_ / 32), 256, 0, stream>>>(Wh1, Wh1T, U_, U_, U_);

    // phase p: layer0 writes h0[p] -> h0b[p&1], reads h0[p-1] -> h0b[(p&1)^1];
    //          layer1 writes h1[p-1] -> h1b[(p&1)^1], reads h1[p-2] -> h1b[p&1]
    dim3 grid(B_ / 128, 2 * (U_ / 64));   // 32 x 32 = 1024 blocks -> 3/CU resident + backfill
    for (int p = 0; p <= T_; ++p) {
        const int e = p & 1;
        rnn_phase<<<grid, 256, 0, stream>>>(embP, inputs + p,
                                            Wx0T, Wh0T, b0, Wx1T, Wh1T, b1,
                                            h0b[e ^ 1], h0b[e], h1b[e], h1b[e ^ 1],
                                            (int)(p < T_), (int)(p >= 1));
    }
    // h1[79] written at phase 80 into h1b[(80&1)^1] = h1b[1]
    final_dense<<<B_ / 4, 256, 0, stream>>>(h1b[1], Wfc, bfc, (float*)d_out);
}

// Round 10
// 3991.373 us; speedup vs baseline: 1.0025x; 1.0025x over previous
//
#include <hip/hip_runtime.h>
#include <stdint.h>

#define B_ 4096
#define T_ 80
#define E_ 100
#define V_ 10000
#define U_ 1024

typedef unsigned short u16;
typedef __attribute__((ext_vector_type(8))) __bf16 bf16x8;
typedef __attribute__((ext_vector_type(4))) float f32x4;

__device__ __forceinline__ float bf2f(u16 u) {
    union { unsigned int i; float f; } v; v.i = ((unsigned int)u) << 16; return v.f;
}
__device__ __forceinline__ u16 f2bf(float f) {
    union { float f; unsigned int i; } v; v.f = f;
    unsigned int x = v.i;
    return (u16)((x + 0x7fffu + ((x >> 16) & 1u)) >> 16);
}

// async global->LDS, 16 B per lane; LDS dest = wave-uniform base + lane*16 (m104 semantics).
__device__ __forceinline__ void load16(const void* g, void* l) {
    __builtin_amdgcn_global_load_lds(
        (__attribute__((address_space(1))) void*)(uintptr_t)g,
        (__attribute__((address_space(3))) void*)(uint32_t)(uintptr_t)l,
        16, 0, 0);
}

// dst[n*Kp + k] = bf16( (k < K) ? src[k*N + n] : 0 )
__global__ void transpose_pad(const float* __restrict__ src, u16* __restrict__ dst,
                              int K, int N, int Kp)
{
    __shared__ u16 tile[32][33];
    const int k0 = blockIdx.x * 32;
    const int n0 = blockIdx.y * 32;
    const int tx = threadIdx.x & 31;
    const int ty = threadIdx.x >> 5;
#pragma unroll
    for (int i = 0; i < 4; i++) {
        int k = k0 + ty + i * 8;
        tile[ty + i * 8][tx] = (k < K) ? f2bf(src[(size_t)k * N + (n0 + tx)]) : (u16)0;
    }
    __syncthreads();
#pragma unroll
    for (int i = 0; i < 4; i++) {
        int n = n0 + ty + i * 8;
        dst[(size_t)n * Kp + (k0 + tx)] = tile[tx][ty + i * 8];
    }
}

__global__ void embed_pad(const float* __restrict__ emb, u16* __restrict__ dst)
{
    int id = blockIdx.x * 256 + threadIdx.x;
    int v = id >> 7, k = id & 127;
    dst[id] = (k < E_) ? f2bf(emb[v * E_ + k]) : (u16)0;
}

// Fused phase p (independent sub-steps):
//   layer0: h0[p]   = tanh(embP[idx_p] @ Wx0 + h0[p-1] @ Wh0 + b0)   (if do0)
//   layer1: h1[p-1] = tanh(h0[p-1] @ Wx1 + h1[p-2] @ Wh1 + b1)       (if do1)
// Round-8 structure (proven best): tile M=128 x N=64, BK=64, dbuf, __syncthreads,
// LDS 48 KB -> 3 blocks/CU. NEW: XCD-aware block mapping (bid%8 = XCD round-robin):
//   XCD c = layer*4 + n-group(4 n-tiles); k = bid>>3: n-in-group fastest, then m.
// Effects: per-XCD weight slice (256 cols x K = 0.5-1.05 MB) stays L2-resident; the 4
// n-blocks sharing an A-tile are co-resident on one XCD (adjacent k) -> A hits L2 after
// one L3 fetch. Layers segregated by XCD (no cross-thrash). Mapping is perf-only.
__global__ void __launch_bounds__(256, 3)
rnn_phase(const u16* __restrict__ embP, const int* __restrict__ idx,
          const u16* __restrict__ Wx0T, const u16* __restrict__ Wh0T, const float* __restrict__ b0,
          const u16* __restrict__ Wx1T, const u16* __restrict__ Wh1T, const float* __restrict__ b1,
          const u16* __restrict__ h0r, u16* __restrict__ h0w,
          const u16* __restrict__ h1r, u16* __restrict__ h1w,
          int do0, int do1)
{
    const int bid = blockIdx.x;
    const int c   = bid & 7;          // XCD (HW round-robins bid % 8)
    const int k   = bid >> 3;         // 0..127 within XCD
    const int layer = c >> 2;         // XCDs 0-3: layer0, 4-7: layer1
    if (layer ? !do1 : !do0) return;
    const int n0 = ((c & 3) * 4 + (k & 3)) * 64;   // n-group(XCD) + n-in-group (fastest)
    const int m0 = (k >> 2) * 128;                 // m streams within XCD

    __shared__ u16 As[2][128 * 64];   // 2 x 16 KB
    __shared__ u16 Bs[2][64 * 64];    // 2 x 8 KB
    const int tid  = threadIdx.x;
    const int lane = tid & 63;
    const int wave = tid >> 6;
    const int wm = wave >> 1, wn = wave & 1;

    const u16 *A1, *W1, *A2, *W2; const float* bias; u16* C; int K1; bool gather;
    if (layer == 0) { A1 = embP; W1 = Wx0T; K1 = 128;  gather = true;  A2 = h0r; W2 = Wh0T; bias = b0; C = h0w; }
    else            { A1 = h0r;  W1 = Wx1T; K1 = 1024; gather = false; A2 = h1r; W2 = Wh1T; bias = b1; C = h1w; }
    const int KB1 = K1 >> 6;            // 64-wide K blocks in the first segment
    const int TOT = KB1 + (U_ >> 6);    // + 16 for the hidden segment

    // staging geometry: per wave, A covers rows [wave*32, wave*32+32) in 4 calls,
    // B covers rows [wave*16, wave*16+16) in 2 calls. lane -> row += (lane>>3), chunk lane&7.
    const int r8 = lane >> 3;           // 0..7
    const int c8 = lane & 7;            // chunk index 0..7

    int gv[4];
    if (gather) {
#pragma unroll
        for (int cc = 0; cc < 4; cc++)
            gv[cc] = idx[(size_t)(m0 + wave * 32 + cc * 8 + r8) * T_];
    }

    const f32x4 z = {0.f, 0.f, 0.f, 0.f};
    f32x4 acc[4][2];
#pragma unroll
    for (int i = 0; i < 4; i++)
#pragma unroll
        for (int j = 0; j < 2; j++) acc[i][j] = z;

    // loop-invariant fragment read offsets (u16 elems), inverse-swizzled
    const int l15 = lane & 15, q = lane >> 4, l7 = lane & 7;
    int offA[2][4], offB[2][2];
#pragma unroll
    for (int kk = 0; kk < 2; kk++) {
#pragma unroll
        for (int f = 0; f < 4; f++) {
            const int rA = wm * 64 + f * 16 + l15;
            offA[kk][f] = rA * 64 + (((kk * 4 + q) ^ l7) * 8);
        }
#pragma unroll
        for (int f = 0; f < 2; f++) {
            const int rB = wn * 32 + f * 16 + l15;
            offB[kk][f] = rB * 64 + (((kk * 4 + q) ^ l7) * 8);
        }
    }

    auto stage = [&](int u, int p) {
        u16* Ad = As[p] + wave * 2048;   // 32 rows x 64 elems
        u16* Bd = Bs[p] + wave * 1024;   // 16 rows x 64 elems
        if (u < KB1) {
            const int k0 = u * 64;
#pragma unroll
            for (int cc = 0; cc < 4; cc++) {
                const int row = wave * 32 + cc * 8 + r8;
                const int scw = (c8 ^ (row & 7)) * 8;
                const u16* ap = gather ? A1 + (size_t)gv[cc] * 128 + k0 + scw
                                       : A1 + (size_t)(m0 + row) * K1 + k0 + scw;
                load16(ap, Ad + cc * 512);
            }
#pragma unroll
            for (int cc = 0; cc < 2; cc++) {
                const int row = wave * 16 + cc * 8 + r8;
                const int scw = (c8 ^ (row & 7)) * 8;
                load16(W1 + (size_t)(n0 + row) * K1 + k0 + scw, Bd + cc * 512);
            }
        } else {
            const int k0 = (u - KB1) * 64;
#pragma unroll
            for (int cc = 0; cc < 4; cc++) {
                const int row = wave * 32 + cc * 8 + r8;
                const int scw = (c8 ^ (row & 7)) * 8;
                load16(A2 + (size_t)(m0 + row) * U_ + k0 + scw, Ad + cc * 512);
            }
#pragma unroll
            for (int cc = 0; cc < 2; cc++) {
                const int row = wave * 16 + cc * 8 + r8;
                const int scw = (c8 ^ (row & 7)) * 8;
                load16(W2 + (size_t)(n0 + row) * U_ + k0 + scw, Bd + cc * 512);
            }
        }
    };

    stage(0, 0);

#pragma unroll 1
    for (int u = 0; u < TOT; ++u) {
        const int p = u & 1;
        __syncthreads();                       // vmcnt(0) drain -> buf[p] ready
        if (u + 1 < TOT) stage(u + 1, p ^ 1);  // flight overlaps this iter's compute
        bf16x8 a[2][4], b[2][2];
#pragma unroll
        for (int kk = 0; kk < 2; kk++) {
#pragma unroll
            for (int f = 0; f < 4; f++)
                a[kk][f] = *reinterpret_cast<const bf16x8*>(As[p] + offA[kk][f]);
#pragma unroll
            for (int f = 0; f < 2; f++)
                b[kk][f] = *reinterpret_cast<const bf16x8*>(Bs[p] + offB[kk][f]);
        }
#pragma unroll
        for (int kk = 0; kk < 2; kk++)
#pragma unroll
            for (int i = 0; i < 4; i++)
#pragma unroll
                for (int j = 0; j < 2; j++)
                    acc[i][j] = __builtin_amdgcn_mfma_f32_16x16x32_bf16(a[kk][i], b[kk][j], acc[i][j], 0, 0, 0);
    }

    // epilogue: bias + tanh, bf16 store (C/D map: col = lane&15, row = (lane>>4)*4 + reg)
#pragma unroll
    for (int j = 0; j < 2; j++) {
        const int col = n0 + wn * 32 + j * 16 + l15;
        const float bv = bias[col];
#pragma unroll
        for (int i = 0; i < 4; i++) {
#pragma unroll
            for (int r = 0; r < 4; r++) {
                const int row = m0 + wm * 64 + i * 16 + (q << 2) + r;
                float x = acc[i][j][r] + bv;
                x = fminf(15.f, fmaxf(-15.f, x));
                float e = __expf(2.f * x);
                C[(size_t)row * U_ + col] = f2bf((e - 1.f) / (e + 1.f));
            }
        }
    }
}

// out[b] = sigmoid( dot(h1[b,:], Wfc) + bfc ), one wave per row; f32 out
__global__ void final_dense(const u16* __restrict__ h1, const float* __restrict__ Wfc,
                            const float* __restrict__ bfc, float* __restrict__ out)
{
    const int lane = threadIdx.x & 63;
    const int wave = threadIdx.x >> 6;
    const int row = blockIdx.x * 4 + wave;
    const u16* hp = h1 + (size_t)row * U_ + lane * 16;
    const float* wp = Wfc + lane * 16;
    float s = 0.f;
#pragma unroll
    for (int i = 0; i < 16; i++) s += bf2f(hp[i]) * wp[i];
#pragma unroll
    for (int off = 32; off; off >>= 1) s += __shfl_down(s, off);
    if (lane == 0) {
        float x = s + bfc[0];
        out[row] = 1.f / (1.f + __expf(-x));
    }
}

extern "C" void kernel_launch(void* const* d_in, const int* in_sizes, int n_in,
                              void* d_out, int out_size, void* d_ws, size_t ws_size,
                              hipStream_t stream)
{
    const int*   inputs = (const int*)d_in[0];
    const float* emb    = (const float*)d_in[1];
    const float* Wx0    = (const float*)d_in[2];
    const float* Wh0    = (const float*)d_in[3];
    const float* b0     = (const float*)d_in[4];
    const float* Wx1    = (const float*)d_in[5];
    const float* Wh1    = (const float*)d_in[6];
    const float* b1     = (const float*)d_in[7];
    const float* Wfc    = (const float*)d_in[8];
    const float* bfc    = (const float*)d_in[9];

    char* ws = (char*)d_ws;
    const size_t MB = 1 << 20;
    u16* h0b[2] = { (u16*)(ws + 0 * MB), (u16*)(ws + 8 * MB) };   // 8 MB each
    u16* h1b[2] = { (u16*)(ws + 16 * MB), (u16*)(ws + 24 * MB) };
    u16* embP = (u16*)(ws + 32 * MB);  // 2.56 MB
    u16* Wx0T = (u16*)(ws + 35 * MB);  // [1024][128]
    u16* Wh0T = (u16*)(ws + 36 * MB);  // [1024][1024]
    u16* Wx1T = (u16*)(ws + 38 * MB);
    u16* Wh1T = (u16*)(ws + 40 * MB);  // ..42 MB

    // phase 0 reads h0[-1] from h0b[1]; phase 1 reads h1[-1] from h1b[1]
    hipMemsetAsync(h0b[1], 0, 8 * MB, stream);
    hipMemsetAsync(h1b[1], 0, 8 * MB, stream);

    embed_pad<<<V_ * 128 / 256, 256, 0, stream>>>(emb, embP);
    transpose_pad<<<dim3(128 / 32, U_ / 32), 256, 0, stream>>>(Wx0, Wx0T, E_, U_, 128);
    transpose_pad<<<dim3(U_ / 32, U_ / 32), 256, 0, stream>>>(Wh0, Wh0T, U_, U_, U_);
    transpose_pad<<<dim3(U_ / 32, U_ / 32), 256, 0, stream>>>(Wx1, Wx1T, U_, U_, U_);
    transpose_pad<<<dim3(U_ / 32, U_ / 32), 256, 0, stream>>>(Wh1, Wh1T, U_, U_, U_);

    // phase p: layer0 writes h0[p] -> h0b[p&1], reads h0[p-1] -> h0b[(p&1)^1];
    //          layer1 writes h1[p-1] -> h1b[(p&1)^1], reads h1[p-2] -> h1b[p&1]
    dim3 grid(1024);   // flat; kernel derives (layer, m0, n0) with bid%8 = XCD
    for (int p = 0; p <= T_; ++p) {
        const int e = p & 1;
        rnn_phase<<<grid, 256, 0, stream>>>(embP, inputs + p,
                                            Wx0T, Wh0T, b0, Wx1T, Wh1T, b1,
                                            h0b[e ^ 1], h0b[e], h1b[e], h1b[e ^ 1],
                                            (int)(p < T_), (int)(p >= 1));
    }
    // h1[79] written at phase 80 into h1b[(80&1)^1] = h1b[1]
    final_dense<<<B_ / 4, 256, 0, stream>>>(h1b[1], Wfc, bfc, (float*)d_out);
}

// Round 11
// 3000.645 us; speedup vs baseline: 1.3335x; 1.3302x over previous
//
#include <hip/hip_runtime.h>
#include <stdint.h>

#define B_ 4096
#define T_ 80
#define E_ 100
#define V_ 10000
#define U_ 1024

typedef unsigned short u16;
typedef __attribute__((ext_vector_type(8))) __bf16 bf16x8;
typedef __attribute__((ext_vector_type(4))) float f32x4;

__device__ __forceinline__ float bf2f(u16 u) {
    union { unsigned int i; float f; } v; v.i = ((unsigned int)u) << 16; return v.f;
}
__device__ __forceinline__ u16 f2bf(float f) {
    union { float f; unsigned int i; } v; v.f = f;
    unsigned int x = v.i;
    return (u16)((x + 0x7fffu + ((x >> 16) & 1u)) >> 16);
}

// async global->LDS, 16 B per lane; LDS dest = wave-uniform base + lane*16 (m104 semantics).
__device__ __forceinline__ void load16(const void* g, void* l) {
    __builtin_amdgcn_global_load_lds(
        (__attribute__((address_space(1))) void*)(uintptr_t)g,
        (__attribute__((address_space(3))) void*)(uint32_t)(uintptr_t)l,
        16, 0, 0);
}

// dst[n*Kp + k] = bf16( (k < K) ? src[k*N + n] : 0 )
__global__ void transpose_pad(const float* __restrict__ src, u16* __restrict__ dst,
                              int K, int N, int Kp)
{
    __shared__ u16 tile[32][33];
    const int k0 = blockIdx.x * 32;
    const int n0 = blockIdx.y * 32;
    const int tx = threadIdx.x & 31;
    const int ty = threadIdx.x >> 5;
#pragma unroll
    for (int i = 0; i < 4; i++) {
        int k = k0 + ty + i * 8;
        tile[ty + i * 8][tx] = (k < K) ? f2bf(src[(size_t)k * N + (n0 + tx)]) : (u16)0;
    }
    __syncthreads();
#pragma unroll
    for (int i = 0; i < 4; i++) {
        int n = n0 + ty + i * 8;
        dst[(size_t)n * Kp + (k0 + tx)] = tile[tx][ty + i * 8];
    }
}

__global__ void embed_pad(const float* __restrict__ emb, u16* __restrict__ dst)
{
    int id = blockIdx.x * 256 + threadIdx.x;
    int v = id >> 7, k = id & 127;
    dst[id] = (k < E_) ? f2bf(emb[v * E_ + k]) : (u16)0;
}

// Fused phase p (independent sub-steps):
//   layer0: h0[p]   = tanh(embP[idx_p] @ Wx0 + h0[p-1] @ Wh0 + b0)   (if do0)
//   layer1: h1[p-1] = tanh(h0[p-1] @ Wx1 + h1[p-2] @ Wh1 + b1)       (if do1)
// Tile M=128 x N=128 (wave tile 64x64, 4x4 frags), BK=64, dbuf -> 64 KB LDS ->
// 2 blocks/CU, grid 512 = all-resident. Rationale (r10 post-mortem): LDS pipe was
// oversubscribed at r8's 64x32 wave tile (10.9 kMAC/b128); 64x64 gives 16.4 kMAC/b128
// (+50% arithmetic intensity per LDS byte) and halves staged DMA bytes per FLOP.
// XOR swizzle (r6-proven, 0 conflicts): LDS row r chunk c holds global chunk c^(r&7);
// readers inverse-XOR with lane&7 (== row&7 since frag rows = multiples of 16 + l15).
__global__ void __launch_bounds__(256, 2)
rnn_phase(const u16* __restrict__ embP, const int* __restrict__ idx,
          const u16* __restrict__ Wx0T, const u16* __restrict__ Wh0T, const float* __restrict__ b0,
          const u16* __restrict__ Wx1T, const u16* __restrict__ Wh1T, const float* __restrict__ b1,
          const u16* __restrict__ h0r, u16* __restrict__ h0w,
          const u16* __restrict__ h1r, u16* __restrict__ h1w,
          int do0, int do1)
{
    const int layer = blockIdx.y & 1;
    if (layer ? !do1 : !do0) return;

    __shared__ u16 As[2][128 * 64];   // 2 x 16 KB
    __shared__ u16 Bs[2][128 * 64];   // 2 x 16 KB
    const int tid  = threadIdx.x;
    const int lane = tid & 63;
    const int wave = tid >> 6;
    const int wm = wave >> 1, wn = wave & 1;
    const int m0 = blockIdx.x * 128;
    const int n0 = (blockIdx.y >> 1) * 128;

    const u16 *A1, *W1, *A2, *W2; const float* bias; u16* C; int K1; bool gather;
    if (layer == 0) { A1 = embP; W1 = Wx0T; K1 = 128;  gather = true;  A2 = h0r; W2 = Wh0T; bias = b0; C = h0w; }
    else            { A1 = h0r;  W1 = Wx1T; K1 = 1024; gather = false; A2 = h1r; W2 = Wh1T; bias = b1; C = h1w; }
    const int KB1 = K1 >> 6;            // 64-wide K blocks in the first segment
    const int TOT = KB1 + (U_ >> 6);    // + 16 for the hidden segment

    // staging: per wave, A rows [wave*32,+32) in 4 calls, B rows [wave*32,+32) in 4 calls.
    // lane -> row += (lane>>3), chunk lane&7, source col chunk = (lane&7) ^ (row&7).
    const int r8 = lane >> 3;           // 0..7
    const int c8 = lane & 7;            // chunk index 0..7

    int gv[4];
    if (gather) {
#pragma unroll
        for (int cc = 0; cc < 4; cc++)
            gv[cc] = idx[(size_t)(m0 + wave * 32 + cc * 8 + r8) * T_];
    }

    const f32x4 z = {0.f, 0.f, 0.f, 0.f};
    f32x4 acc[4][4];
#pragma unroll
    for (int i = 0; i < 4; i++)
#pragma unroll
        for (int j = 0; j < 4; j++) acc[i][j] = z;

    // loop-invariant fragment read offsets (u16 elems), inverse-swizzled
    const int l15 = lane & 15, q = lane >> 4, l7 = lane & 7;
    int offA[2][4], offB[2][4];
#pragma unroll
    for (int kk = 0; kk < 2; kk++) {
#pragma unroll
        for (int f = 0; f < 4; f++) {
            const int rA = wm * 64 + f * 16 + l15;
            const int rB = wn * 64 + f * 16 + l15;
            offA[kk][f] = rA * 64 + (((kk * 4 + q) ^ l7) * 8);
            offB[kk][f] = rB * 64 + (((kk * 4 + q) ^ l7) * 8);
        }
    }

    auto stage = [&](int u, int p) {
        u16* Ad = As[p] + wave * 2048;   // 32 rows x 64 elems
        u16* Bd = Bs[p] + wave * 2048;   // 32 rows x 64 elems
        if (u < KB1) {
            const int k0 = u * 64;
#pragma unroll
            for (int cc = 0; cc < 4; cc++) {
                const int row = wave * 32 + cc * 8 + r8;
                const int scw = (c8 ^ (row & 7)) * 8;
                const u16* ap = gather ? A1 + (size_t)gv[cc] * 128 + k0 + scw
                                       : A1 + (size_t)(m0 + row) * K1 + k0 + scw;
                load16(ap, Ad + cc * 512);
                load16(W1 + (size_t)(n0 + row) * K1 + k0 + scw, Bd + cc * 512);
            }
        } else {
            const int k0 = (u - KB1) * 64;
#pragma unroll
            for (int cc = 0; cc < 4; cc++) {
                const int row = wave * 32 + cc * 8 + r8;
                const int scw = (c8 ^ (row & 7)) * 8;
                load16(A2 + (size_t)(m0 + row) * U_ + k0 + scw, Ad + cc * 512);
                load16(W2 + (size_t)(n0 + row) * U_ + k0 + scw, Bd + cc * 512);
            }
        }
    };

    stage(0, 0);

#pragma unroll 1
    for (int u = 0; u < TOT; ++u) {
        const int p = u & 1;
        __syncthreads();                       // vmcnt(0) drain -> buf[p] ready
        if (u + 1 < TOT) stage(u + 1, p ^ 1);  // flight overlaps this iter's compute
#pragma unroll
        for (int kk = 0; kk < 2; kk++) {
            bf16x8 a[4], b[4];
#pragma unroll
            for (int f = 0; f < 4; f++) {
                a[f] = *reinterpret_cast<const bf16x8*>(As[p] + offA[kk][f]);
                b[f] = *reinterpret_cast<const bf16x8*>(Bs[p] + offB[kk][f]);
            }
#pragma unroll
            for (int i = 0; i < 4; i++)
#pragma unroll
                for (int j = 0; j < 4; j++)
                    acc[i][j] = __builtin_amdgcn_mfma_f32_16x16x32_bf16(a[i], b[j], acc[i][j], 0, 0, 0);
        }
    }

    // epilogue: bias + tanh, bf16 store (C/D map: col = lane&15, row = (lane>>4)*4 + reg)
#pragma unroll
    for (int j = 0; j < 4; j++) {
        const int col = n0 + wn * 64 + j * 16 + l15;
        const float bv = bias[col];
#pragma unroll
        for (int i = 0; i < 4; i++) {
#pragma unroll
            for (int r = 0; r < 4; r++) {
                const int row = m0 + wm * 64 + i * 16 + (q << 2) + r;
                float x = acc[i][j][r] + bv;
                x = fminf(15.f, fmaxf(-15.f, x));
                float e = __expf(2.f * x);
                C[(size_t)row * U_ + col] = f2bf((e - 1.f) / (e + 1.f));
            }
        }
    }
}

// out[b] = sigmoid( dot(h1[b,:], Wfc) + bfc ), one wave per row; f32 out
__global__ void final_dense(const u16* __restrict__ h1, const float* __restrict__ Wfc,
                            const float* __restrict__ bfc, float* __restrict__ out)
{
    const int lane = threadIdx.x & 63;
    const int wave = threadIdx.x >> 6;
    const int row = blockIdx.x * 4 + wave;
    const u16* hp = h1 + (size_t)row * U_ + lane * 16;
    const float* wp = Wfc + lane * 16;
    float s = 0.f;
#pragma unroll
    for (int i = 0; i < 16; i++) s += bf2f(hp[i]) * wp[i];
#pragma unroll
    for (int off = 32; off; off >>= 1) s += __shfl_down(s, off);
    if (lane == 0) {
        float x = s + bfc[0];
        out[row] = 1.f / (1.f + __expf(-x));
    }
}

extern "C" void kernel_launch(void* const* d_in, const int* in_sizes, int n_in,
                              void* d_out, int out_size, void* d_ws, size_t ws_size,
                              hipStream_t stream)
{
    const int*   inputs = (const int*)d_in[0];
    const float* emb    = (const float*)d_in[1];
    const float* Wx0    = (const float*)d_in[2];
    const float* Wh0    = (const float*)d_in[3];
    const float* b0     = (const float*)d_in[4];
    const float* Wx1    = (const float*)d_in[5];
    const float* Wh1    = (const float*)d_in[6];
    const float* b1     = (const float*)d_in[7];
    const float* Wfc    = (const float*)d_in[8];
    const float* bfc    = (const float*)d_in[9];

    char* ws = (char*)d_ws;
    const size_t MB = 1 << 20;
    u16* h0b[2] = { (u16*)(ws + 0 * MB), (u16*)(ws + 8 * MB) };   // 8 MB each
    u16* h1b[2] = { (u16*)(ws + 16 * MB), (u16*)(ws + 24 * MB) };
    u16* embP = (u16*)(ws + 32 * MB);  // 2.56 MB
    u16* Wx0T = (u16*)(ws + 35 * MB);  // [1024][128]
    u16* Wh0T = (u16*)(ws + 36 * MB);  // [1024][1024]
    u16* Wx1T = (u16*)(ws + 38 * MB);
    u16* Wh1T = (u16*)(ws + 40 * MB);  // ..42 MB

    // phase 0 reads h0[-1] from h0b[1]; phase 1 reads h1[-1] from h1b[1]
    hipMemsetAsync(h0b[1], 0, 8 * MB, stream);
    hipMemsetAsync(h1b[1], 0, 8 * MB, stream);

    embed_pad<<<V_ * 128 / 256, 256, 0, stream>>>(emb, embP);
    transpose_pad<<<dim3(128 / 32, U_ / 32), 256, 0, stream>>>(Wx0, Wx0T, E_, U_, 128);
    transpose_pad<<<dim3(U_ / 32, U_ / 32), 256, 0, stream>>>(Wh0, Wh0T, U_, U_, U_);
    transpose_pad<<<dim3(U_ / 32, U_ / 32), 256, 0, stream>>>(Wx1, Wx1T, U_, U_, U_);
    transpose_pad<<<dim3(U_ / 32, U_ / 32), 256, 0, stream>>>(Wh1, Wh1T, U_, U_, U_);

    // phase p: layer0 writes h0[p] -> h0b[p&1], reads h0[p-1] -> h0b[(p&1)^1];
    //          layer1 writes h1[p-1] -> h1b[(p&1)^1], reads h1[p-2] -> h1b[p&1]
    dim3 grid(B_ / 128, 2 * (U_ / 128));   // 32 x 16 = 512 blocks -> 2/CU, all resident
    for (int p = 0; p <= T_; ++p) {
        const int e = p & 1;
        rnn_phase<<<grid, 256, 0, stream>>>(embP, inputs + p,
                                            Wx0T, Wh0T, b0, Wx1T, Wh1T, b1,
                                            h0b[e ^ 1], h0b[e], h1b[e], h1b[e ^ 1],
                                            (int)(p < T_), (int)(p >= 1));
    }
    // h1[79] written at phase 80 into h1b[(80&1)^1] = h1b[1]
    final_dense<<<B_ / 4, 256, 0, stream>>>(h1b[1], Wfc, bfc, (float*)d_out);
}